// Round 5
// baseline (649.337 us; speedup 1.0000x reference)
//
#include <hip/hip_runtime.h>
#include <hip/hip_bf16.h>
#include <stdint.h>

#define Bn 32
#define Tn 2048
#define Hn 1024
#define Cn 1024

typedef short short8 __attribute__((ext_vector_type(8)));
typedef float floatx4 __attribute__((ext_vector_type(4)));

__device__ __forceinline__ unsigned int bf16_rne(float f) {
    union { float f; unsigned int u; } v; v.f = f;
    unsigned int u = v.u;
    return (u + 0x7fffu + ((u >> 16) & 1u)) >> 16;
}

// Fused preprocessing: blocks 0..511 compute dbias partials, blocks 512..1023
// pack V. grid 1024 x 256.
// dbp[(b*4+z)][c] = sum_{h in z-chunk} dec[b][h]*W[h][c] (+ bias at z==0)
// vp[(nt*32 + kt)*64 + lane] holds 8 bf16: V[kt*32+(lane>>4)*8+j][nt*16+(lane&15)]
__global__ void k_prep(const float* __restrict__ dec, const float* __restrict__ W,
                       const float* __restrict__ bias, const float* __restrict__ V,
                       float* __restrict__ dbp, uint4* __restrict__ vp) {
    if (blockIdx.x < 512) {
        const int blk = blockIdx.x;
        const int b  = blk >> 4;
        const int y  = (blk >> 2) & 3;
        const int z  = blk & 3;
        const int c  = y * 256 + threadIdx.x;
        const int h0 = z * 256;
        const float* dv = dec + b * Hn + h0;
        const float* wp = W + (size_t)h0 * Cn + c;
        float acc = 0.f;
#pragma unroll 8
        for (int h = 0; h < 256; ++h)
            acc += dv[h] * wp[(size_t)h * Cn];
        if (z == 0) acc += bias[c];
        dbp[(size_t)(b * 4 + z) * Cn + c] = acc;
    } else {
        const int vb   = blockIdx.x - 512;       // 0..511
        const int sub  = threadIdx.x >> 6;       // 0..3
        const int lane = threadIdx.x & 63;
        const int bid  = vb * 4 + sub;           // 0..2047
        const int nt   = bid >> 5;
        const int kt   = bid & 31;
        const int c    = nt * 16 + (lane & 15);
        const int k0   = kt * 32 + (lane >> 4) * 8;
        unsigned int h[8];
#pragma unroll
        for (int j = 0; j < 8; ++j)
            h[j] = bf16_rne(V[(size_t)(k0 + j) * Cn + c]);
        uint4 u;
        u.x = h[0] | (h[1] << 16);
        u.y = h[2] | (h[3] << 16);
        u.z = h[4] | (h[5] << 16);
        u.w = h[6] | (h[7] << 16);
        vp[(size_t)bid * 64 + lane] = u;
    }
}

#define BLK_M 64
#define LDA   1032   // 1024 + 8 bf16 pad -> 2064B row stride, conflict-free ds_read_b128

struct ScoresShared {
    unsigned short A[BLK_M * LDA];  // 132096 B
    float scores[BLK_M];
};

// Fused enc_proj GEMM + tanh + dot(w) -> scores[B*T]
// v5: persistent blocks — grid 256 (1/CU), each block does 4 row-tiles.
// The next tile's 64x1024 fp32 panel is loaded into registers (32 float4/thread)
// right after the staging barrier, so its HBM latency/BW hides under this
// tile's ~120K-cycle compute; only tile 0's staging is exposed (was 4x).
// Inner MFMA loop is byte-identical to the 248us-proven v1 structure.
__global__ __launch_bounds__(512, 2)
void k_scores(const float* __restrict__ enc, const uint4* __restrict__ vp,
              const float* __restrict__ dbp, const float* __restrict__ wv,
              float* __restrict__ scores_g) {
    __shared__ ScoresShared sh;
    const int tid  = threadIdx.x;
    const int lane = tid & 63;
    const int wave = tid >> 6;
    const int lhi  = lane >> 4;        // 0..3
    const int llo  = lane & 15;

    float4 fbuf[32];
    // prologue: load tile q=0 into registers
    {
        const float4* ep = (const float4*)(enc + (size_t)(blockIdx.x * 4) * BLK_M * Hn);
#pragma unroll
        for (int i = 0; i < 32; ++i)
            fbuf[i] = ep[tid + i * 512];
    }

    for (int q = 0; q < 4; ++q) {
        const int tile = blockIdx.x * 4 + q;
        const int b    = tile >> 5;          // same b for all 4 tiles of a block
        const int row0 = tile * BLK_M;

        if (tid < BLK_M) sh.scores[tid] = 0.f;

        // Write the register-staged tile to LDS (compiler inserts vmcnt waits).
#pragma unroll
        for (int i = 0; i < 32; ++i) {
            int idx = tid + i * 512;          // 0..16383
            int r   = idx >> 8;               // row 0..63
            int c4  = idx & 255;              // float4 index in row
            uint2 p;
            p.x = bf16_rne(fbuf[i].x) | (bf16_rne(fbuf[i].y) << 16);
            p.y = bf16_rne(fbuf[i].z) | (bf16_rne(fbuf[i].w) << 16);
            *(uint2*)&sh.A[r * LDA + c4 * 4] = p;
        }
        __syncthreads();   // B1: tile staged, sh.scores zeroed

        // Issue next tile's global loads — consumed only at the next write phase.
        if (q < 3) {
            const float4* ep = (const float4*)(enc + (size_t)(tile + 1) * BLK_M * Hn);
#pragma unroll
            for (int i = 0; i < 32; ++i)
                fbuf[i] = ep[tid + i * 512];
        }

        float score_part[16];
#pragma unroll
        for (int i = 0; i < 16; ++i) score_part[i] = 0.f;

        for (int ni = 0; ni < 2; ++ni) {
            const int colbase = (ni * 8 + wave) * 64;
            const int nt0     = colbase >> 4;

            floatx4 acc[4][4];
#pragma unroll
            for (int i = 0; i < 4; ++i)
#pragma unroll
                for (int j = 0; j < 4; ++j)
                    acc[i][j] = (floatx4){0.f, 0.f, 0.f, 0.f};

#pragma unroll 2
            for (int kt = 0; kt < 32; ++kt) {
                short8 afr[4], bfr[4];
#pragma unroll
                for (int rg = 0; rg < 4; ++rg) {
                    const unsigned short* ap = &sh.A[(rg * 16 + llo) * LDA + kt * 32 + lhi * 8];
                    afr[rg] = *(const short8*)ap;
                }
#pragma unroll
                for (int j = 0; j < 4; ++j) {
                    uint4 u = vp[((nt0 + j) * 32 + kt) * 64 + lane];
                    bfr[j] = __builtin_bit_cast(short8, u);
                }
#pragma unroll
                for (int rg = 0; rg < 4; ++rg)
#pragma unroll
                    for (int j = 0; j < 4; ++j)
                        acc[rg][j] = __builtin_amdgcn_mfma_f32_16x16x32_bf16(
                            afr[rg], bfr[j], acc[rg][j], 0, 0, 0);
            }

            // Epilogue: score_part[rg*4+r] += tanh(acc + dbias[c]) * w[c]
#pragma unroll
            for (int j = 0; j < 4; ++j) {
                const int c  = colbase + j * 16 + llo;
                const float db = dbp[(size_t)(b * 4 + 0) * Cn + c]
                               + dbp[(size_t)(b * 4 + 1) * Cn + c]
                               + dbp[(size_t)(b * 4 + 2) * Cn + c]
                               + dbp[(size_t)(b * 4 + 3) * Cn + c];
                const float wc = wv[c];
#pragma unroll
                for (int rg = 0; rg < 4; ++rg) {
#pragma unroll
                    for (int r = 0; r < 4; ++r) {
                        float x = acc[rg][j][r] + db;
                        x = fminf(fmaxf(x, -12.f), 12.f);
                        float e = __expf(2.f * x);
                        float t = 1.f - 2.f / (e + 1.f);
                        score_part[rg * 4 + r] += t * wc;
                    }
                }
            }
        }

        // Reduce over the 16 lanes (llo) that share each row.
#pragma unroll
        for (int i = 0; i < 16; ++i) {
            float v = score_part[i];
            v += __shfl_xor(v, 1);
            v += __shfl_xor(v, 2);
            v += __shfl_xor(v, 4);
            v += __shfl_xor(v, 8);
            score_part[i] = v;
        }
        if (llo == 0) {
#pragma unroll
            for (int rg = 0; rg < 4; ++rg)
#pragma unroll
                for (int r = 0; r < 4; ++r)
                    atomicAdd(&sh.scores[rg * 16 + lhi * 4 + r], score_part[rg * 4 + r]);
        }
        __syncthreads();   // B2: all atomics done; all sh.A reads done
        if (tid < BLK_M) scores_g[row0 + tid] = sh.scores[tid];
        // Next iteration's sh.A writes are ordered after B2; sh.scores re-zero is
        // done by the same threads that stored it (program order). Safe.
    }
}

// context stage 1 with fused softmax: each (b,tc) block recomputes the cheap
// 2048-wide softmax stats, materializes only its own 256 align values in LDS,
// then part[b][tc][h] = sum_{t in chunk} align[t] * enc[b][t][h].
// grid (32, 8) x 256 threads. Plain stores, no atomics.
__global__ void k_ctx1(const float* __restrict__ enc, const float* __restrict__ scores,
                       float* __restrict__ part) {
    const int b   = blockIdx.x;
    const int tc  = blockIdx.y;
    const int tid = threadIdx.x;
    __shared__ float al_sh[256];
    __shared__ float red[4];
    __shared__ float red2[4];

    const float* s = scores + b * Tn;
    float v[8];
    float lmax = -1e30f;
#pragma unroll
    for (int i = 0; i < 8; ++i) { v[i] = s[tid + i * 256]; lmax = fmaxf(lmax, v[i]); }
    for (int off = 1; off < 64; off <<= 1) lmax = fmaxf(lmax, __shfl_xor(lmax, off));
    if ((tid & 63) == 0) red[tid >> 6] = lmax;
    __syncthreads();
    lmax = fmaxf(fmaxf(red[0], red[1]), fmaxf(red[2], red[3]));
    float lsum = 0.f;
#pragma unroll
    for (int i = 0; i < 8; ++i) lsum += __expf(v[i] - lmax);
    for (int off = 1; off < 64; off <<= 1) lsum += __shfl_xor(lsum, off);
    if ((tid & 63) == 0) red2[tid >> 6] = lsum;
    __syncthreads();
    lsum = red2[0] + red2[1] + red2[2] + red2[3];
    const float inv = 1.f / lsum;
    al_sh[tid] = __expf(s[tc * 256 + tid] - lmax) * inv;
    __syncthreads();

    const float4* ep = (const float4*)(enc + ((size_t)b * Tn + tc * 256) * Hn);
    float4 acc = {0.f, 0.f, 0.f, 0.f};
#pragma unroll 4
    for (int t = 0; t < 256; ++t) {
        const float a = al_sh[t];
        const float4 e = ep[t * 256 + tid];
        acc.x += a * e.x; acc.y += a * e.y; acc.z += a * e.z; acc.w += a * e.w;
    }
    ((float4*)part)[(b * 8 + tc) * 256 + tid] = acc;
}

// context stage 2: out[b][h] = sum_tc part[b][tc][h]. grid 32 x 256.
__global__ void k_ctx2(const float* __restrict__ part, float* __restrict__ out) {
    const int b   = blockIdx.x;
    const int tid = threadIdx.x;
    const float4* pp = (const float4*)part;
    float4 s = {0.f, 0.f, 0.f, 0.f};
#pragma unroll
    for (int tc = 0; tc < 8; ++tc) {
        float4 p = pp[(b * 8 + tc) * 256 + tid];
        s.x += p.x; s.y += p.y; s.z += p.z; s.w += p.w;
    }
    ((float4*)out)[b * 256 + tid] = s;
}

extern "C" void kernel_launch(void* const* d_in, const int* in_sizes, int n_in,
                              void* d_out, int out_size, void* d_ws, size_t ws_size,
                              hipStream_t stream) {
    const float* dec  = (const float*)d_in[0];   // [32,1,1024]
    const float* enc  = (const float*)d_in[1];   // [32,2048,1024]
    const float* W    = (const float*)d_in[2];   // [1024,1024]
    const float* V    = (const float*)d_in[3];   // [1024,1024]
    const float* bias = (const float*)d_in[4];   // [1024]
    const float* wv   = (const float*)d_in[5];   // [1024,1]
    float* out = (float*)d_out;                  // [32,1024]

    char* ws = (char*)d_ws;
    float* dbp    = (float*)(ws);                              // 512 KB
    uint4* vpack  = (uint4*)(ws + 524288);                     // 2 MB
    float* scores = (float*)(ws + 524288 + 2097152);           // 256 KB
    float* cpart  = (float*)(ws + 524288 + 2097152 + 262144);  // 1 MB

    k_prep  <<<1024, 256, 0, stream>>>(dec, W, bias, V, dbp, vpack);
    k_scores<<<256, 512, 0, stream>>>(enc, vpack, dbp, wv, scores);
    k_ctx1  <<<dim3(32, 8), 256, 0, stream>>>(enc, scores, cpart);
    k_ctx2  <<<32, 256, 0, stream>>>(cpart, out);
}

// Round 6
// 562.669 us; speedup vs baseline: 1.1540x; 1.1540x over previous
//
#include <hip/hip_runtime.h>
#include <hip/hip_bf16.h>
#include <stdint.h>

#define Bn 32
#define Tn 2048
#define Hn 1024
#define Cn 1024

typedef short short8 __attribute__((ext_vector_type(8)));
typedef float floatx4 __attribute__((ext_vector_type(4)));

__device__ __forceinline__ unsigned int bf16_rne(float f) {
    union { float f; unsigned int u; } v; v.f = f;
    unsigned int u = v.u;
    return (u + 0x7fffu + ((u >> 16) & 1u)) >> 16;
}

// Fused preprocessing: blocks 0..511 compute dbias partials, blocks 512..1023
// pack V. grid 1024 x 256.
// dbp[(b*4+z)][c] = sum_{h in z-chunk} dec[b][h]*W[h][c] (+ bias at z==0)
// vp[(nt*32 + kt)*64 + lane] holds 8 bf16: V[kt*32+(lane>>4)*8+j][nt*16+(lane&15)]
__global__ void k_prep(const float* __restrict__ dec, const float* __restrict__ W,
                       const float* __restrict__ bias, const float* __restrict__ V,
                       float* __restrict__ dbp, uint4* __restrict__ vp) {
    if (blockIdx.x < 512) {
        const int blk = blockIdx.x;
        const int b  = blk >> 4;
        const int y  = (blk >> 2) & 3;
        const int z  = blk & 3;
        const int c  = y * 256 + threadIdx.x;
        const int h0 = z * 256;
        const float* dv = dec + b * Hn + h0;
        const float* wp = W + (size_t)h0 * Cn + c;
        float acc = 0.f;
#pragma unroll 8
        for (int h = 0; h < 256; ++h)
            acc += dv[h] * wp[(size_t)h * Cn];
        if (z == 0) acc += bias[c];
        dbp[(size_t)(b * 4 + z) * Cn + c] = acc;
    } else {
        const int vb   = blockIdx.x - 512;       // 0..511
        const int sub  = threadIdx.x >> 6;       // 0..3
        const int lane = threadIdx.x & 63;
        const int bid  = vb * 4 + sub;           // 0..2047
        const int nt   = bid >> 5;
        const int kt   = bid & 31;
        const int c    = nt * 16 + (lane & 15);
        const int k0   = kt * 32 + (lane >> 4) * 8;
        unsigned int h[8];
#pragma unroll
        for (int j = 0; j < 8; ++j)
            h[j] = bf16_rne(V[(size_t)(k0 + j) * Cn + c]);
        uint4 u;
        u.x = h[0] | (h[1] << 16);
        u.y = h[2] | (h[3] << 16);
        u.z = h[4] | (h[5] << 16);
        u.w = h[6] | (h[7] << 16);
        vp[(size_t)bid * 64 + lane] = u;
    }
}

#define BLK_M 64
#define LDA   1032   // 1024 + 8 bf16 pad -> 2064B row stride, conflict-free ds_read_b128

struct ScoresShared {
    unsigned short A[BLK_M * LDA];  // 132096 B
    float scores[BLK_M];
};

// Fused enc_proj GEMM + tanh + dot(w) -> scores[B*T]
// grid 1024 x 512 threads (8 waves). Wave computes 64 rows x 64 cols per N-iter.
// v6: byte-identical to the 248us-proven v4 structure (whole-tile register
// prefetch in v5 spilled to scratch: WRITE_SIZE 256KB->40MB, reverted).
__global__ __launch_bounds__(512, 2)
void k_scores(const float* __restrict__ enc, const uint4* __restrict__ vp,
              const float* __restrict__ dbp, const float* __restrict__ wv,
              float* __restrict__ scores_g) {
    __shared__ ScoresShared sh;
    const int wg   = blockIdx.x;
    const int tid  = threadIdx.x;
    const int lane = tid & 63;
    const int wave = tid >> 6;
    const int b    = wg >> 5;          // 32 WGs per batch row-block
    const int row0 = wg * BLK_M;
    const int lhi  = lane >> 4;        // 0..3
    const int llo  = lane & 15;

    if (tid < BLK_M) sh.scores[tid] = 0.f;

    // Stage A (64 rows x 1024 fp32) -> bf16 LDS, coalesced float4 loads.
    {
        const float4* ep = (const float4*)(enc + (size_t)row0 * Hn);
#pragma unroll 4
        for (int it = 0; it < 32; ++it) {
            int idx = tid + it * 512;         // 0..16383
            int r   = idx >> 8;               // row 0..63
            int c4  = idx & 255;              // float4 index in row
            float4 f = ep[r * 256 + c4];
            uint2 p;
            p.x = bf16_rne(f.x) | (bf16_rne(f.y) << 16);
            p.y = bf16_rne(f.z) | (bf16_rne(f.w) << 16);
            *(uint2*)&sh.A[r * LDA + c4 * 4] = p;
        }
    }
    __syncthreads();   // the only barrier before the epilogue

    float score_part[16];
#pragma unroll
    for (int i = 0; i < 16; ++i) score_part[i] = 0.f;

    for (int ni = 0; ni < 2; ++ni) {
        const int colbase = (ni * 8 + wave) * 64;
        const int nt0     = colbase >> 4;

        floatx4 acc[4][4];
#pragma unroll
        for (int i = 0; i < 4; ++i)
#pragma unroll
            for (int j = 0; j < 4; ++j)
                acc[i][j] = (floatx4){0.f, 0.f, 0.f, 0.f};

#pragma unroll 2
        for (int kt = 0; kt < 32; ++kt) {
            short8 afr[4], bfr[4];
#pragma unroll
            for (int rg = 0; rg < 4; ++rg) {
                const unsigned short* ap = &sh.A[(rg * 16 + llo) * LDA + kt * 32 + lhi * 8];
                afr[rg] = *(const short8*)ap;
            }
#pragma unroll
            for (int j = 0; j < 4; ++j) {
                uint4 u = vp[((nt0 + j) * 32 + kt) * 64 + lane];
                bfr[j] = __builtin_bit_cast(short8, u);
            }
#pragma unroll
            for (int rg = 0; rg < 4; ++rg)
#pragma unroll
                for (int j = 0; j < 4; ++j)
                    acc[rg][j] = __builtin_amdgcn_mfma_f32_16x16x32_bf16(
                        afr[rg], bfr[j], acc[rg][j], 0, 0, 0);
        }

        // Epilogue: score_part[rg*4+r] += tanh(acc + dbias[c]) * w[c]
#pragma unroll
        for (int j = 0; j < 4; ++j) {
            const int c  = colbase + j * 16 + llo;
            const float db = dbp[(size_t)(b * 4 + 0) * Cn + c]
                           + dbp[(size_t)(b * 4 + 1) * Cn + c]
                           + dbp[(size_t)(b * 4 + 2) * Cn + c]
                           + dbp[(size_t)(b * 4 + 3) * Cn + c];
            const float wc = wv[c];
#pragma unroll
            for (int rg = 0; rg < 4; ++rg) {
#pragma unroll
                for (int r = 0; r < 4; ++r) {
                    float x = acc[rg][j][r] + db;
                    x = fminf(fmaxf(x, -12.f), 12.f);
                    float e = __expf(2.f * x);
                    float t = 1.f - 2.f / (e + 1.f);
                    score_part[rg * 4 + r] += t * wc;
                }
            }
        }
    }

    // Reduce over the 16 lanes (llo) that share each row.
#pragma unroll
    for (int i = 0; i < 16; ++i) {
        float v = score_part[i];
        v += __shfl_xor(v, 1);
        v += __shfl_xor(v, 2);
        v += __shfl_xor(v, 4);
        v += __shfl_xor(v, 8);
        score_part[i] = v;
    }
    if (llo == 0) {
#pragma unroll
        for (int rg = 0; rg < 4; ++rg)
#pragma unroll
            for (int r = 0; r < 4; ++r)
                atomicAdd(&sh.scores[rg * 16 + lhi * 4 + r], score_part[rg * 4 + r]);
    }
    __syncthreads();
    if (tid < BLK_M) scores_g[row0 + tid] = sh.scores[tid];
}

// context stage 1 with fused softmax, v6: grid (32, 32) x 256 — 4 blocks/CU,
// 4 waves/SIMD (was 1), 64 t-rows per block, t-loop unrolled 8. The block
// recomputes the cheap 2048-wide softmax stats (scores are L2-hot), applies
// softmax only to its own 64 rows, accumulates partial context, plain store.
__global__ void k_ctx1(const float* __restrict__ enc, const float* __restrict__ scores,
                       float* __restrict__ part) {
    const int b   = blockIdx.x;
    const int tc  = blockIdx.y;          // 0..31, 64 t-rows each
    const int tid = threadIdx.x;
    __shared__ float al_sh[64];
    __shared__ float red[4];
    __shared__ float red2[4];

    const float* s = scores + b * Tn;
    float v[8];
    float lmax = -1e30f;
#pragma unroll
    for (int i = 0; i < 8; ++i) { v[i] = s[tid + i * 256]; lmax = fmaxf(lmax, v[i]); }
    for (int off = 1; off < 64; off <<= 1) lmax = fmaxf(lmax, __shfl_xor(lmax, off));
    if ((tid & 63) == 0) red[tid >> 6] = lmax;
    __syncthreads();
    lmax = fmaxf(fmaxf(red[0], red[1]), fmaxf(red[2], red[3]));
    float lsum = 0.f;
#pragma unroll
    for (int i = 0; i < 8; ++i) lsum += __expf(v[i] - lmax);
    for (int off = 1; off < 64; off <<= 1) lsum += __shfl_xor(lsum, off);
    if ((tid & 63) == 0) red2[tid >> 6] = lsum;
    __syncthreads();
    lsum = red2[0] + red2[1] + red2[2] + red2[3];
    const float inv = 1.f / lsum;
    if (tid < 64) al_sh[tid] = __expf(s[tc * 64 + tid] - lmax) * inv;
    __syncthreads();

    const float4* ep = (const float4*)(enc + ((size_t)b * Tn + tc * 64) * Hn);
    float4 acc = {0.f, 0.f, 0.f, 0.f};
#pragma unroll 8
    for (int t = 0; t < 64; ++t) {
        const float a = al_sh[t];
        const float4 e = ep[t * 256 + tid];
        acc.x += a * e.x; acc.y += a * e.y; acc.z += a * e.z; acc.w += a * e.w;
    }
    ((float4*)part)[(b * 32 + tc) * 256 + tid] = acc;
}

// context stage 2: out[b][h] = sum_tc part[b][tc][h]. grid 32 x 256.
__global__ void k_ctx2(const float* __restrict__ part, float* __restrict__ out) {
    const int b   = blockIdx.x;
    const int tid = threadIdx.x;
    const float4* pp = (const float4*)part;
    float4 s = {0.f, 0.f, 0.f, 0.f};
#pragma unroll
    for (int tc = 0; tc < 32; ++tc) {
        float4 p = pp[(b * 32 + tc) * 256 + tid];
        s.x += p.x; s.y += p.y; s.z += p.z; s.w += p.w;
    }
    ((float4*)out)[b * 256 + tid] = s;
}

extern "C" void kernel_launch(void* const* d_in, const int* in_sizes, int n_in,
                              void* d_out, int out_size, void* d_ws, size_t ws_size,
                              hipStream_t stream) {
    const float* dec  = (const float*)d_in[0];   // [32,1,1024]
    const float* enc  = (const float*)d_in[1];   // [32,2048,1024]
    const float* W    = (const float*)d_in[2];   // [1024,1024]
    const float* V    = (const float*)d_in[3];   // [1024,1024]
    const float* bias = (const float*)d_in[4];   // [1024]
    const float* wv   = (const float*)d_in[5];   // [1024,1]
    float* out = (float*)d_out;                  // [32,1024]

    char* ws = (char*)d_ws;
    float* dbp    = (float*)(ws);                              // 512 KB
    uint4* vpack  = (uint4*)(ws + 524288);                     // 2 MB
    float* scores = (float*)(ws + 524288 + 2097152);           // 256 KB
    float* cpart  = (float*)(ws + 524288 + 2097152 + 262144);  // 4 MB

    k_prep  <<<1024, 256, 0, stream>>>(dec, W, bias, V, dbp, vpack);
    k_scores<<<1024, 512, 0, stream>>>(enc, vpack, dbp, wv, scores);
    k_ctx1  <<<dim3(32, 32), 256, 0, stream>>>(enc, scores, cpart);
    k_ctx2  <<<32, 256, 0, stream>>>(cpart, out);
}

// Round 7
// 554.465 us; speedup vs baseline: 1.1711x; 1.0148x over previous
//
#include <hip/hip_runtime.h>
#include <hip/hip_bf16.h>
#include <stdint.h>

#define Bn 32
#define Tn 2048
#define Hn 1024
#define Cn 1024

typedef short short8 __attribute__((ext_vector_type(8)));
typedef float floatx4 __attribute__((ext_vector_type(4)));

__device__ __forceinline__ unsigned int bf16_rne(float f) {
    union { float f; unsigned int u; } v; v.f = f;
    unsigned int u = v.u;
    return (u + 0x7fffu + ((u >> 16) & 1u)) >> 16;
}

// Fused preprocessing: blocks 0..511 compute dbias partials, blocks 512..1023
// pack V. grid 1024 x 256.
// dbp[(b*4+z)][c] = sum_{h in z-chunk} dec[b][h]*W[h][c] (+ bias at z==0)
// vp[(nt*32 + kt)*64 + lane] holds 8 bf16: V[kt*32+(lane>>4)*8+j][nt*16+(lane&15)]
__global__ void k_prep(const float* __restrict__ dec, const float* __restrict__ W,
                       const float* __restrict__ bias, const float* __restrict__ V,
                       float* __restrict__ dbp, uint4* __restrict__ vp) {
    if (blockIdx.x < 512) {
        const int blk = blockIdx.x;
        const int b  = blk >> 4;
        const int y  = (blk >> 2) & 3;
        const int z  = blk & 3;
        const int c  = y * 256 + threadIdx.x;
        const int h0 = z * 256;
        const float* dv = dec + b * Hn + h0;
        const float* wp = W + (size_t)h0 * Cn + c;
        float acc = 0.f;
#pragma unroll 8
        for (int h = 0; h < 256; ++h)
            acc += dv[h] * wp[(size_t)h * Cn];
        if (z == 0) acc += bias[c];
        dbp[(size_t)(b * 4 + z) * Cn + c] = acc;
    } else {
        const int vb   = blockIdx.x - 512;       // 0..511
        const int sub  = threadIdx.x >> 6;       // 0..3
        const int lane = threadIdx.x & 63;
        const int bid  = vb * 4 + sub;           // 0..2047
        const int nt   = bid >> 5;
        const int kt   = bid & 31;
        const int c    = nt * 16 + (lane & 15);
        const int k0   = kt * 32 + (lane >> 4) * 8;
        unsigned int h[8];
#pragma unroll
        for (int j = 0; j < 8; ++j)
            h[j] = bf16_rne(V[(size_t)(k0 + j) * Cn + c]);
        uint4 u;
        u.x = h[0] | (h[1] << 16);
        u.y = h[2] | (h[3] << 16);
        u.z = h[4] | (h[5] << 16);
        u.w = h[6] | (h[7] << 16);
        vp[(size_t)bid * 64 + lane] = u;
    }
}

#define BLK_M 64
#define LDA   1032   // 1024 + 8 bf16 pad -> 2064B row stride, conflict-free ds_read_b128

struct ScoresShared {
    unsigned short A[BLK_M * LDA];  // 132096 B
    float scores[BLK_M];
};

// Fused enc_proj GEMM + tanh + dot(w) -> scores[B*T]
// v7: 1024-thread blocks (16 waves) on the same 64-row tile — 4 waves/SIMD
// instead of 2 at identical LDS footprint, identical total LDS/L2/MFMA
// traffic, identical inner-loop body. Each wave owns 64 rows x 64 cols in a
// single pass (colbase = wave*64); the ni loop is gone. Pure TLP for the
// latency-bound regime (MfmaUtil 24%, VALUBusy 28%, both pipes idle at 2
// waves/SIMD).
__global__ __launch_bounds__(1024, 4)
void k_scores(const float* __restrict__ enc, const uint4* __restrict__ vp,
              const float* __restrict__ dbp, const float* __restrict__ wv,
              float* __restrict__ scores_g) {
    __shared__ ScoresShared sh;
    const int wg   = blockIdx.x;
    const int tid  = threadIdx.x;
    const int lane = tid & 63;
    const int wave = tid >> 6;         // 0..15
    const int b    = wg >> 5;          // 32 WGs per batch row-block
    const int row0 = wg * BLK_M;
    const int lhi  = lane >> 4;        // 0..3
    const int llo  = lane & 15;

    if (tid < BLK_M) sh.scores[tid] = 0.f;

    // Stage A (64 rows x 1024 fp32) -> bf16 LDS, coalesced float4 loads.
    {
        const float4* ep = (const float4*)(enc + (size_t)row0 * Hn);
#pragma unroll 4
        for (int it = 0; it < 16; ++it) {
            int idx = tid + it * 1024;        // 0..16383
            int r   = idx >> 8;               // row 0..63
            int c4  = idx & 255;              // float4 index in row
            float4 f = ep[r * 256 + c4];
            uint2 p;
            p.x = bf16_rne(f.x) | (bf16_rne(f.y) << 16);
            p.y = bf16_rne(f.z) | (bf16_rne(f.w) << 16);
            *(uint2*)&sh.A[r * LDA + c4 * 4] = p;
        }
    }
    __syncthreads();   // the only barrier before the epilogue

    float score_part[16];
#pragma unroll
    for (int i = 0; i < 16; ++i) score_part[i] = 0.f;

    const int colbase = wave * 64;
    const int nt0     = wave * 4;

    floatx4 acc[4][4];
#pragma unroll
    for (int i = 0; i < 4; ++i)
#pragma unroll
        for (int j = 0; j < 4; ++j)
            acc[i][j] = (floatx4){0.f, 0.f, 0.f, 0.f};

#pragma unroll 2
    for (int kt = 0; kt < 32; ++kt) {
        short8 afr[4], bfr[4];
#pragma unroll
        for (int rg = 0; rg < 4; ++rg) {
            const unsigned short* ap = &sh.A[(rg * 16 + llo) * LDA + kt * 32 + lhi * 8];
            afr[rg] = *(const short8*)ap;
        }
#pragma unroll
        for (int j = 0; j < 4; ++j) {
            uint4 u = vp[((nt0 + j) * 32 + kt) * 64 + lane];
            bfr[j] = __builtin_bit_cast(short8, u);
        }
#pragma unroll
        for (int rg = 0; rg < 4; ++rg)
#pragma unroll
            for (int j = 0; j < 4; ++j)
                acc[rg][j] = __builtin_amdgcn_mfma_f32_16x16x32_bf16(
                    afr[rg], bfr[j], acc[rg][j], 0, 0, 0);
    }

    // Epilogue: score_part[rg*4+r] += tanh(acc + dbias[c]) * w[c]
#pragma unroll
    for (int j = 0; j < 4; ++j) {
        const int c  = colbase + j * 16 + llo;
        const float db = dbp[(size_t)(b * 4 + 0) * Cn + c]
                       + dbp[(size_t)(b * 4 + 1) * Cn + c]
                       + dbp[(size_t)(b * 4 + 2) * Cn + c]
                       + dbp[(size_t)(b * 4 + 3) * Cn + c];
        const float wc = wv[c];
#pragma unroll
        for (int rg = 0; rg < 4; ++rg) {
#pragma unroll
            for (int r = 0; r < 4; ++r) {
                float x = acc[rg][j][r] + db;
                x = fminf(fmaxf(x, -12.f), 12.f);
                float e = __expf(2.f * x);
                float t = 1.f - 2.f / (e + 1.f);
                score_part[rg * 4 + r] += t * wc;
            }
        }
    }

    // Reduce over the 16 lanes (llo) that share each row.
#pragma unroll
    for (int i = 0; i < 16; ++i) {
        float v = score_part[i];
        v += __shfl_xor(v, 1);
        v += __shfl_xor(v, 2);
        v += __shfl_xor(v, 4);
        v += __shfl_xor(v, 8);
        score_part[i] = v;
    }
    if (llo == 0) {
#pragma unroll
        for (int rg = 0; rg < 4; ++rg)
#pragma unroll
            for (int r = 0; r < 4; ++r)
                atomicAdd(&sh.scores[rg * 16 + lhi * 4 + r], score_part[rg * 4 + r]);
    }
    __syncthreads();
    if (tid < BLK_M) scores_g[row0 + tid] = sh.scores[tid];
}

// context stage 1 with fused softmax: grid (32, 32) x 256 — 4 blocks/CU,
// 64 t-rows per block, t-loop unrolled 8. The block recomputes the cheap
// 2048-wide softmax stats (scores are L2-hot), applies softmax only to its
// own 64 rows, accumulates partial context, plain store.
__global__ void k_ctx1(const float* __restrict__ enc, const float* __restrict__ scores,
                       float* __restrict__ part) {
    const int b   = blockIdx.x;
    const int tc  = blockIdx.y;          // 0..31, 64 t-rows each
    const int tid = threadIdx.x;
    __shared__ float al_sh[64];
    __shared__ float red[4];
    __shared__ float red2[4];

    const float* s = scores + b * Tn;
    float v[8];
    float lmax = -1e30f;
#pragma unroll
    for (int i = 0; i < 8; ++i) { v[i] = s[tid + i * 256]; lmax = fmaxf(lmax, v[i]); }
    for (int off = 1; off < 64; off <<= 1) lmax = fmaxf(lmax, __shfl_xor(lmax, off));
    if ((tid & 63) == 0) red[tid >> 6] = lmax;
    __syncthreads();
    lmax = fmaxf(fmaxf(red[0], red[1]), fmaxf(red[2], red[3]));
    float lsum = 0.f;
#pragma unroll
    for (int i = 0; i < 8; ++i) lsum += __expf(v[i] - lmax);
    for (int off = 1; off < 64; off <<= 1) lsum += __shfl_xor(lsum, off);
    if ((tid & 63) == 0) red2[tid >> 6] = lsum;
    __syncthreads();
    lsum = red2[0] + red2[1] + red2[2] + red2[3];
    const float inv = 1.f / lsum;
    if (tid < 64) al_sh[tid] = __expf(s[tc * 64 + tid] - lmax) * inv;
    __syncthreads();

    const float4* ep = (const float4*)(enc + ((size_t)b * Tn + tc * 64) * Hn);
    float4 acc = {0.f, 0.f, 0.f, 0.f};
#pragma unroll 8
    for (int t = 0; t < 64; ++t) {
        const float a = al_sh[t];
        const float4 e = ep[t * 256 + tid];
        acc.x += a * e.x; acc.y += a * e.y; acc.z += a * e.z; acc.w += a * e.w;
    }
    ((float4*)part)[(b * 32 + tc) * 256 + tid] = acc;
}

// context stage 2: out[b][h] = sum_tc part[b][tc][h]. grid 32 x 256.
__global__ void k_ctx2(const float* __restrict__ part, float* __restrict__ out) {
    const int b   = blockIdx.x;
    const int tid = threadIdx.x;
    const float4* pp = (const float4*)part;
    float4 s = {0.f, 0.f, 0.f, 0.f};
#pragma unroll
    for (int tc = 0; tc < 32; ++tc) {
        float4 p = pp[(b * 32 + tc) * 256 + tid];
        s.x += p.x; s.y += p.y; s.z += p.z; s.w += p.w;
    }
    ((float4*)out)[b * 256 + tid] = s;
}

extern "C" void kernel_launch(void* const* d_in, const int* in_sizes, int n_in,
                              void* d_out, int out_size, void* d_ws, size_t ws_size,
                              hipStream_t stream) {
    const float* dec  = (const float*)d_in[0];   // [32,1,1024]
    const float* enc  = (const float*)d_in[1];   // [32,2048,1024]
    const float* W    = (const float*)d_in[2];   // [1024,1024]
    const float* V    = (const float*)d_in[3];   // [1024,1024]
    const float* bias = (const float*)d_in[4];   // [1024]
    const float* wv   = (const float*)d_in[5];   // [1024,1]
    float* out = (float*)d_out;                  // [32,1024]

    char* ws = (char*)d_ws;
    float* dbp    = (float*)(ws);                              // 512 KB
    uint4* vpack  = (uint4*)(ws + 524288);                     // 2 MB
    float* scores = (float*)(ws + 524288 + 2097152);           // 256 KB
    float* cpart  = (float*)(ws + 524288 + 2097152 + 262144);  // 4 MB

    k_prep  <<<1024, 256, 0, stream>>>(dec, W, bias, V, dbp, vpack);
    k_scores<<<1024, 1024, 0, stream>>>(enc, vpack, dbp, wv, scores);
    k_ctx1  <<<dim3(32, 32), 256, 0, stream>>>(enc, scores, cpart);
    k_ctx2  <<<32, 256, 0, stream>>>(cpart, out);
}